// Round 12
// baseline (987.374 us; speedup 1.0000x reference)
//
#include <hip/hip_runtime.h>
#include <stdint.h>

#define T_TOK 8192
#define DD 1024
#define FF 4096
#define EE 16
#define MAX_SLOTS 18432 // 16384 + 16*127 padded to 128
#define MT 144          // max 128-row m-tiles

typedef __attribute__((ext_vector_type(4))) float f32x4;
typedef __attribute__((ext_vector_type(8))) short bf16x8;

__device__ __forceinline__ unsigned short f2bf(float f) {
  union { float f; unsigned u; } v; v.f = f;
  unsigned r = v.u + 0x7FFFu + ((v.u >> 16) & 1u);
  return (unsigned short)(r >> 16);
}

__device__ __forceinline__ void gload16(const void* g, void* l) {
  __builtin_amdgcn_global_load_lds(
      (const __attribute__((address_space(1))) unsigned int*)g,
      (__attribute__((address_space(3))) unsigned int*)l, 16, 0, 0);
}

// ---------------- router ------------------------------------------------------
__global__ void router_kernel(const float* __restrict__ x, const float* __restrict__ Wr,
                              const float* __restrict__ br,
                              int* __restrict__ counts, int* __restrict__ tok_e,
                              int* __restrict__ tok_s, float* __restrict__ tok_w,
                              int* __restrict__ elist) {
  int t = blockIdx.x * blockDim.x + threadIdx.x;
  if (t >= T_TOK) return;
  float acc[EE];
#pragma unroll
  for (int e = 0; e < EE; ++e) acc[e] = br[e];
  const f32x4* x4 = (const f32x4*)(x + (size_t)t * DD);
  for (int d4 = 0; d4 < DD / 4; ++d4) {
    f32x4 xv = x4[d4];
    const float* wr = Wr + (size_t)d4 * 4 * EE;
#pragma unroll
    for (int dd = 0; dd < 4; ++dd)
#pragma unroll
      for (int e = 0; e < EE; ++e) acc[e] += xv[dd] * wr[dd * EE + e];
  }
  int i0 = 0; float v0 = acc[0];
#pragma unroll
  for (int e = 1; e < EE; ++e) if (acc[e] > v0) { v0 = acc[e]; i0 = e; }
  int i1 = -1; float v1 = -3.4e38f;
#pragma unroll
  for (int e = 0; e < EE; ++e) if (e != i0 && acc[e] > v1) { v1 = acc[e]; i1 = e; }
  float p1 = __expf(v1 - v0);
  float w0 = 1.f / (1.f + p1);
  float w1 = p1 * w0;
  int s0 = atomicAdd(&counts[i0], 1);
  int s1 = atomicAdd(&counts[i1], 1);
  tok_e[2 * t] = i0; tok_s[2 * t] = s0; tok_w[2 * t] = w0;
  tok_e[2 * t + 1] = i1; tok_s[2 * t + 1] = s1; tok_w[2 * t + 1] = w1;
  elist[(size_t)i0 * T_TOK + s0] = t;
  elist[(size_t)i1 * T_TOK + s1] = t;
}

// ---------------- scan (pad to 128) -------------------------------------------
__global__ void scan_kernel(const int* __restrict__ counts, int* __restrict__ off,
                            int* __restrict__ mtb) {
  if (threadIdx.x == 0 && blockIdx.x == 0) {
    int o = 0, m = 0;
    for (int e = 0; e < EE; ++e) {
      off[e] = o; mtb[e] = m;
      int c = counts[e];
      int mt = (c + 127) / 128;
      o += mt * 128; m += mt;
    }
    off[EE] = o; mtb[EE] = m;
  }
}

// ---------------- gather ------------------------------------------------------
__global__ void gather_kernel(const float* __restrict__ x, const int* __restrict__ counts,
                              const int* __restrict__ off, const int* __restrict__ elist,
                              unsigned short* __restrict__ Xg) {
  int slot = blockIdx.x;
  if (slot >= off[EE]) return;
  int e = 0;
  while (e < EE - 1 && off[e + 1] <= slot) ++e;
  int s = slot - off[e];
  int tid = threadIdx.x;
  ushort4* dst = (ushort4*)(Xg + (size_t)slot * DD);
  if (s < counts[e]) {
    int t = elist[(size_t)e * T_TOK + s];
    f32x4 v = ((const f32x4*)(x + (size_t)t * DD))[tid];
    ushort4 o;
    o.x = f2bf(v[0]); o.y = f2bf(v[1]); o.z = f2bf(v[2]); o.w = f2bf(v[3]);
    dst[tid] = o;
  } else {
    ushort4 z; z.x = z.y = z.z = z.w = 0;
    dst[tid] = z;
  }
}

// ---------------- transpose+convert fp32[R][C] -> bf16[C][R], 16B both ways ---
__global__ void transpose_conv(const float* __restrict__ src0, unsigned short* __restrict__ dst0,
                               int R, int C) {
  __shared__ float tile[128][65];
  int e = blockIdx.z;
  const float* src = src0 + (size_t)e * R * C;
  unsigned short* dst = dst0 + (size_t)e * R * C;
  int r0 = blockIdx.y * 128, c0 = blockIdx.x * 64;
  int tid = threadIdx.x;
  int lc = (tid & 15) * 4, lr = tid >> 4;
#pragma unroll
  for (int p = 0; p < 8; ++p) {
    int r = p * 16 + lr;
    f32x4 v = *(const f32x4*)(src + (size_t)(r0 + r) * C + c0 + lc);
    tile[r][lc + 0] = v[0]; tile[r][lc + 1] = v[1];
    tile[r][lc + 2] = v[2]; tile[r][lc + 3] = v[3];
  }
  __syncthreads();
  int sc = tid >> 4, sr = (tid & 15) * 8;
#pragma unroll
  for (int p = 0; p < 4; ++p) {
    int c = p * 16 + sc;
    unsigned short tmp[8];
#pragma unroll
    for (int j = 0; j < 8; ++j) tmp[j] = f2bf(tile[sr + j][c]);
    *(bf16x8*)(dst + (size_t)(c0 + c) * R + r0 + sr) = *(const bf16x8*)tmp;
  }
}

// ---------------- GEMM1: 128x128, BK=64, swizzled LDS (R8-proven) -------------
// LDS panels [128 rows][128B]: LDS[row][chunk ch] = G[row][k0 + (ch^(row&7))*8]
// (both-sides swizzle). Fragment read chunk lc = kk*4 + (lane>>4); phys = lc^(fr&7).
// launch_bounds (256,2): 256 regs/wave -> 100 VGPR + 128 acc, NO spill.
__global__ __launch_bounds__(256, 2) void gemm1_kernel(
    const unsigned short* __restrict__ Xg, const unsigned short* __restrict__ W1t,
    const unsigned short* __restrict__ W3t, const int* __restrict__ off,
    const int* __restrict__ mtb, unsigned short* __restrict__ H) {
  __shared__ __align__(16) char lds[49152];  // A@0, B1@16384, B3@32768
  int bx = blockIdx.x;          // n-block fastest: L3-friendly expert sweep
  int by = blockIdx.y;
  if (by >= mtb[EE]) return;
  int e = 0;
  while (e < EE - 1 && mtb[e + 1] <= by) ++e;
  int m0 = off[e] + (by - mtb[e]) * 128;
  int n0 = bx * 128;
  const unsigned short* A = Xg + (size_t)m0 * DD;
  const unsigned short* B1 = W1t + ((size_t)e * FF + n0) * DD;
  const unsigned short* B3 = W3t + ((size_t)e * FF + n0) * DD;
  int tid = threadIdx.x, lane = tid & 63, wid = tid >> 6;
  int wm = wid >> 1, wn = wid & 1;
  int fr = lane & 15, fk4 = lane >> 4;
  int swz = fr & 7;
  int ce8 = (((tid & 7) ^ ((tid >> 3) & 7)) << 3);
  const unsigned short* AgT = A + (size_t)(tid >> 3) * DD + ce8;
  const unsigned short* B1T = B1 + (size_t)(tid >> 3) * DD + ce8;
  const unsigned short* B3T = B3 + (size_t)(tid >> 3) * DD + ce8;
  char* ldsW = lds + tid * 16;

  f32x4 acc1[4][4] = {}, acc3[4][4] = {};

  for (int k0 = 0; k0 < DD; k0 += 64) {
#pragma unroll
    for (int j = 0; j < 4; ++j) {
      gload16(AgT + (size_t)j * 32 * DD + k0, ldsW + j * 4096);
      gload16(B1T + (size_t)j * 32 * DD + k0, ldsW + 16384 + j * 4096);
      gload16(B3T + (size_t)j * 32 * DD + k0, ldsW + 32768 + j * 4096);
    }
    __syncthreads();
#pragma unroll
    for (int kk = 0; kk < 2; ++kk) {
      int pc = ((kk * 4 + fk4) ^ swz) << 4;  // phys chunk byte offset
      bf16x8 a[4], b1[4], b3[4];
#pragma unroll
      for (int mi = 0; mi < 4; ++mi)
        a[mi] = *(const bf16x8*)(lds + (wm * 64 + mi * 16 + fr) * 128 + pc);
#pragma unroll
      for (int ni = 0; ni < 4; ++ni) {
        b1[ni] = *(const bf16x8*)(lds + 16384 + (wn * 64 + ni * 16 + fr) * 128 + pc);
        b3[ni] = *(const bf16x8*)(lds + 32768 + (wn * 64 + ni * 16 + fr) * 128 + pc);
      }
#pragma unroll
      for (int mi = 0; mi < 4; ++mi)
#pragma unroll
        for (int ni = 0; ni < 4; ++ni) {
          acc1[mi][ni] = __builtin_amdgcn_mfma_f32_16x16x32_bf16(a[mi], b1[ni], acc1[mi][ni], 0, 0, 0);
          acc3[mi][ni] = __builtin_amdgcn_mfma_f32_16x16x32_bf16(a[mi], b3[ni], acc3[mi][ni], 0, 0, 0);
        }
    }
    __syncthreads();
  }
#pragma unroll
  for (int mi = 0; mi < 4; ++mi)
#pragma unroll
    for (int ni = 0; ni < 4; ++ni)
#pragma unroll
      for (int i = 0; i < 4; ++i) {
        int row = m0 + wm * 64 + mi * 16 + (lane >> 4) * 4 + i;
        int col = n0 + wn * 64 + ni * 16 + (lane & 15);
        float c1 = acc1[mi][ni][i], c3 = acc3[mi][ni][i];
        float h = c1 / (1.f + __expf(-c1)) * c3;
        H[(size_t)row * FF + col] = f2bf(h);
      }
}

// ---------------- GEMM2: Y = H @ W2t, 128x128, BK=128 -------------------------
// BK=128 doubles MFMA per barrier-pair to 64 (gemm1's proven ratio). LDS 64KB
// (A 32K + B 32K) keeps 2 blocks/CU (regs already cap waves at 2/SIMD).
// Rows are 256B = 16 chunks: LDS[row][ch] = G[row][k0 + (ch^(row&15))*8];
// fragment chunk lc = kk*4 + fk4, phys = lc ^ fr (2-way alias only = free).
__global__ __launch_bounds__(256, 2) void gemm2_kernel(
    const unsigned short* __restrict__ H, const unsigned short* __restrict__ W2t,
    const int* __restrict__ off, const int* __restrict__ mtb, float* __restrict__ Y) {
  __shared__ __align__(16) char lds[65536];  // A@0 (32KB), B@32768 (32KB)
  int bx = blockIdx.x;
  int by = blockIdx.y;
  if (by >= mtb[EE]) return;
  int e = 0;
  while (e < EE - 1 && mtb[e + 1] <= by) ++e;
  int m0 = off[e] + (by - mtb[e]) * 128;
  int n0 = bx * 128;
  const unsigned short* A = H + (size_t)m0 * FF;
  const unsigned short* B = W2t + ((size_t)e * DD + n0) * FF;
  int tid = threadIdx.x, lane = tid & 63, wid = tid >> 6;
  int wm = wid >> 1, wn = wid & 1;
  int fr = lane & 15, fk4 = lane >> 4;
  // staging: 16 threads/row (16B chunks over 256B), 16 rows/pass, 8 passes
  int ce8 = (((tid & 15) ^ ((tid >> 4) & 15)) << 3);
  const unsigned short* AgT = A + (size_t)(tid >> 4) * FF + ce8;
  const unsigned short* BgT = B + (size_t)(tid >> 4) * FF + ce8;
  char* ldsW = lds + tid * 16;

  f32x4 acc[4][4] = {};

  for (int k0 = 0; k0 < FF; k0 += 128) {
#pragma unroll
    for (int p = 0; p < 8; ++p) {
      gload16(AgT + (size_t)p * 16 * FF + k0, ldsW + p * 4096);
      gload16(BgT + (size_t)p * 16 * FF + k0, ldsW + 32768 + p * 4096);
    }
    __syncthreads();
#pragma unroll
    for (int kk = 0; kk < 4; ++kk) {
      int pc = ((kk * 4 + fk4) ^ fr) << 4;  // phys chunk byte offset (16 chunks)
      bf16x8 a[4], b[4];
#pragma unroll
      for (int mi = 0; mi < 4; ++mi)
        a[mi] = *(const bf16x8*)(lds + (wm * 64 + mi * 16 + fr) * 256 + pc);
#pragma unroll
      for (int ni = 0; ni < 4; ++ni)
        b[ni] = *(const bf16x8*)(lds + 32768 + (wn * 64 + ni * 16 + fr) * 256 + pc);
#pragma unroll
      for (int mi = 0; mi < 4; ++mi)
#pragma unroll
        for (int ni = 0; ni < 4; ++ni)
          acc[mi][ni] = __builtin_amdgcn_mfma_f32_16x16x32_bf16(a[mi], b[ni], acc[mi][ni], 0, 0, 0);
    }
    __syncthreads();
  }
#pragma unroll
  for (int mi = 0; mi < 4; ++mi)
#pragma unroll
    for (int ni = 0; ni < 4; ++ni)
#pragma unroll
      for (int i = 0; i < 4; ++i) {
        int row = m0 + wm * 64 + mi * 16 + (lane >> 4) * 4 + i;
        int col = n0 + wn * 64 + ni * 16 + (lane & 15);
        Y[(size_t)row * DD + col] = acc[mi][ni][i];
      }
}

// ---------------- LayerNorm + weighted combine ---------------------------------
__global__ void ln_combine_kernel(const float* __restrict__ Y, const int* __restrict__ tok_e,
                                  const int* __restrict__ tok_s, const float* __restrict__ tok_w,
                                  const int* __restrict__ off, const float* __restrict__ gamma,
                                  const float* __restrict__ beta, float* __restrict__ out) {
  int t = blockIdx.x, tid = threadIdx.x;
  __shared__ float red[8];
  f32x4 o = {0.f, 0.f, 0.f, 0.f};
  for (int k = 0; k < 2; ++k) {
    int e = tok_e[2 * t + k], s = tok_s[2 * t + k];
    float w = tok_w[2 * t + k];
    int slot = off[e] + s;
    f32x4 v = ((const f32x4*)(Y + (size_t)slot * DD))[tid];
    float sum = v[0] + v[1] + v[2] + v[3];
    float sq = v[0] * v[0] + v[1] * v[1] + v[2] * v[2] + v[3] * v[3];
    for (int d = 32; d > 0; d >>= 1) {
      sum += __shfl_down(sum, d);
      sq += __shfl_down(sq, d);
    }
    int wv = tid >> 6, lane = tid & 63;
    if (lane == 0) { red[wv * 2] = sum; red[wv * 2 + 1] = sq; }
    __syncthreads();
    float S1 = red[0] + red[2] + red[4] + red[6];
    float S2 = red[1] + red[3] + red[5] + red[7];
    __syncthreads();
    float mu = S1 * (1.f / (float)DD);
    float var = S2 * (1.f / (float)DD) - mu * mu;
    float rs = rsqrtf(var + 1e-5f);
    f32x4 g = ((const f32x4*)(gamma + (size_t)e * DD))[tid];
    f32x4 b = ((const f32x4*)(beta + (size_t)e * DD))[tid];
#pragma unroll
    for (int j = 0; j < 4; ++j) o[j] += w * ((v[j] - mu) * rs * g[j] + b[j]);
  }
  ((f32x4*)out)[(size_t)t * (DD / 4) + tid] = o;
}

// ---------------- launch -------------------------------------------------------
extern "C" void kernel_launch(void* const* d_in, const int* in_sizes, int n_in,
                              void* d_out, int out_size, void* d_ws, size_t ws_size,
                              hipStream_t stream) {
  const float* x = (const float*)d_in[0];
  const float* Wr = (const float*)d_in[1];
  const float* br = (const float*)d_in[2];
  const float* W1 = (const float*)d_in[3];
  const float* W3 = (const float*)d_in[4];
  const float* W2 = (const float*)d_in[5];
  const float* gamma = (const float*)d_in[6];
  const float* beta = (const float*)d_in[7];
  float* out = (float*)d_out;

  char* w = (char*)d_ws;
  size_t o = 0;
  auto alloc = [&](size_t bytes) {
    void* p = w + o;
    o += (bytes + 255) & ~(size_t)255;
    return p;
  };
  int* counts = (int*)alloc(EE * 4);
  int* off = (int*)alloc((EE + 1) * 4);
  int* mtb = (int*)alloc((EE + 1) * 4);
  int* tok_e = (int*)alloc(2 * T_TOK * 4);
  int* tok_s = (int*)alloc(2 * T_TOK * 4);
  float* tok_w = (float*)alloc(2 * T_TOK * 4);
  int* elist = (int*)alloc((size_t)EE * T_TOK * 4);
  unsigned short* Xg = (unsigned short*)alloc((size_t)MAX_SLOTS * DD * 2);
  unsigned short* W1t = (unsigned short*)alloc((size_t)EE * DD * FF * 2);
  unsigned short* W3t = (unsigned short*)alloc((size_t)EE * DD * FF * 2);
  unsigned short* W2t = (unsigned short*)alloc((size_t)EE * DD * FF * 2);
  unsigned short* Hb = (unsigned short*)alloc((size_t)MAX_SLOTS * FF * 2);
  float* Y = (float*)alloc((size_t)MAX_SLOTS * DD * 4);

  hipMemsetAsync(counts, 0, EE * sizeof(int), stream);
  router_kernel<<<T_TOK / 256, 256, 0, stream>>>(x, Wr, br, counts, tok_e, tok_s, tok_w, elist);
  scan_kernel<<<1, 64, 0, stream>>>(counts, off, mtb);
  gather_kernel<<<MAX_SLOTS, 256, 0, stream>>>(x, counts, off, elist, Xg);
  transpose_conv<<<dim3(FF / 64, DD / 128, EE), 256, 0, stream>>>(W1, W1t, DD, FF);
  transpose_conv<<<dim3(FF / 64, DD / 128, EE), 256, 0, stream>>>(W3, W3t, DD, FF);
  transpose_conv<<<dim3(DD / 64, FF / 128, EE), 256, 0, stream>>>(W2, W2t, FF, DD);
  gemm1_kernel<<<dim3(FF / 128, MT), 256, 0, stream>>>(Xg, W1t, W3t, off, mtb, Hb);
  gemm2_kernel<<<dim3(DD / 128, MT), 256, 0, stream>>>(Hb, W2t, off, mtb, Y);
  ln_combine_kernel<<<T_TOK, 256, 0, stream>>>(Y, tok_e, tok_s, tok_w, off, gamma, beta, out);
}

// Round 13
// 964.565 us; speedup vs baseline: 1.0236x; 1.0236x over previous
//
#include <hip/hip_runtime.h>
#include <stdint.h>

#define T_TOK 8192
#define DD 1024
#define FF 4096
#define EE 16
#define MAX_SLOTS 18432 // 16384 + 16*127 padded to 128
#define MT 144          // max 128-row m-tiles

typedef __attribute__((ext_vector_type(4))) float f32x4;
typedef __attribute__((ext_vector_type(8))) short bf16x8;

__device__ __forceinline__ unsigned short f2bf(float f) {
  union { float f; unsigned u; } v; v.f = f;
  unsigned r = v.u + 0x7FFFu + ((v.u >> 16) & 1u);
  return (unsigned short)(r >> 16);
}

__device__ __forceinline__ void gload16(const void* g, void* l) {
  __builtin_amdgcn_global_load_lds(
      (const __attribute__((address_space(1))) unsigned int*)g,
      (__attribute__((address_space(3))) unsigned int*)l, 16, 0, 0);
}

// ---------------- router ------------------------------------------------------
__global__ void router_kernel(const float* __restrict__ x, const float* __restrict__ Wr,
                              const float* __restrict__ br,
                              int* __restrict__ counts, int* __restrict__ tok_e,
                              int* __restrict__ tok_s, float* __restrict__ tok_w,
                              int* __restrict__ elist) {
  int t = blockIdx.x * blockDim.x + threadIdx.x;
  if (t >= T_TOK) return;
  float acc[EE];
#pragma unroll
  for (int e = 0; e < EE; ++e) acc[e] = br[e];
  const f32x4* x4 = (const f32x4*)(x + (size_t)t * DD);
  for (int d4 = 0; d4 < DD / 4; ++d4) {
    f32x4 xv = x4[d4];
    const float* wr = Wr + (size_t)d4 * 4 * EE;
#pragma unroll
    for (int dd = 0; dd < 4; ++dd)
#pragma unroll
      for (int e = 0; e < EE; ++e) acc[e] += xv[dd] * wr[dd * EE + e];
  }
  int i0 = 0; float v0 = acc[0];
#pragma unroll
  for (int e = 1; e < EE; ++e) if (acc[e] > v0) { v0 = acc[e]; i0 = e; }
  int i1 = -1; float v1 = -3.4e38f;
#pragma unroll
  for (int e = 0; e < EE; ++e) if (e != i0 && acc[e] > v1) { v1 = acc[e]; i1 = e; }
  float p1 = __expf(v1 - v0);
  float w0 = 1.f / (1.f + p1);
  float w1 = p1 * w0;
  int s0 = atomicAdd(&counts[i0], 1);
  int s1 = atomicAdd(&counts[i1], 1);
  tok_e[2 * t] = i0; tok_s[2 * t] = s0; tok_w[2 * t] = w0;
  tok_e[2 * t + 1] = i1; tok_s[2 * t + 1] = s1; tok_w[2 * t + 1] = w1;
  elist[(size_t)i0 * T_TOK + s0] = t;
  elist[(size_t)i1 * T_TOK + s1] = t;
}

// ---------------- scan (pad to 128) -------------------------------------------
__global__ void scan_kernel(const int* __restrict__ counts, int* __restrict__ off,
                            int* __restrict__ mtb) {
  if (threadIdx.x == 0 && blockIdx.x == 0) {
    int o = 0, m = 0;
    for (int e = 0; e < EE; ++e) {
      off[e] = o; mtb[e] = m;
      int c = counts[e];
      int mt = (c + 127) / 128;
      o += mt * 128; m += mt;
    }
    off[EE] = o; mtb[EE] = m;
  }
}

// ---------------- gather ------------------------------------------------------
__global__ void gather_kernel(const float* __restrict__ x, const int* __restrict__ counts,
                              const int* __restrict__ off, const int* __restrict__ elist,
                              unsigned short* __restrict__ Xg) {
  int slot = blockIdx.x;
  if (slot >= off[EE]) return;
  int e = 0;
  while (e < EE - 1 && off[e + 1] <= slot) ++e;
  int s = slot - off[e];
  int tid = threadIdx.x;
  ushort4* dst = (ushort4*)(Xg + (size_t)slot * DD);
  if (s < counts[e]) {
    int t = elist[(size_t)e * T_TOK + s];
    f32x4 v = ((const f32x4*)(x + (size_t)t * DD))[tid];
    ushort4 o;
    o.x = f2bf(v[0]); o.y = f2bf(v[1]); o.z = f2bf(v[2]); o.w = f2bf(v[3]);
    dst[tid] = o;
  } else {
    ushort4 z; z.x = z.y = z.z = z.w = 0;
    dst[tid] = z;
  }
}

// ---------------- transpose+convert fp32[R][C] -> bf16[C][R], 16B both ways ---
__global__ void transpose_conv(const float* __restrict__ src0, unsigned short* __restrict__ dst0,
                               int R, int C) {
  __shared__ float tile[128][65];
  int e = blockIdx.z;
  const float* src = src0 + (size_t)e * R * C;
  unsigned short* dst = dst0 + (size_t)e * R * C;
  int r0 = blockIdx.y * 128, c0 = blockIdx.x * 64;
  int tid = threadIdx.x;
  int lc = (tid & 15) * 4, lr = tid >> 4;
#pragma unroll
  for (int p = 0; p < 8; ++p) {
    int r = p * 16 + lr;
    f32x4 v = *(const f32x4*)(src + (size_t)(r0 + r) * C + c0 + lc);
    tile[r][lc + 0] = v[0]; tile[r][lc + 1] = v[1];
    tile[r][lc + 2] = v[2]; tile[r][lc + 3] = v[3];
  }
  __syncthreads();
  int sc = tid >> 4, sr = (tid & 15) * 8;
#pragma unroll
  for (int p = 0; p < 4; ++p) {
    int c = p * 16 + sc;
    unsigned short tmp[8];
#pragma unroll
    for (int j = 0; j < 8; ++j) tmp[j] = f2bf(tile[sr + j][c]);
    *(bf16x8*)(dst + (size_t)(c0 + c) * R + r0 + sr) = *(const bf16x8*)tmp;
  }
}

// ---------------- GEMM1: 128x128, BK=64, swizzled LDS (R8-proven) -------------
// LDS panels [128 rows][128B]: LDS[row][chunk ch] = G[row][k0 + (ch^(row&7))*8]
// (both-sides swizzle). Fragment read chunk lc = kk*4 + (lane>>4); phys = lc^(fr&7).
// (256,2): acc1+acc3 = 128 AGPR + ~100 VGPR = 228 -> 2 waves/SIMD, NO spill.
__global__ __launch_bounds__(256, 2) void gemm1_kernel(
    const unsigned short* __restrict__ Xg, const unsigned short* __restrict__ W1t,
    const unsigned short* __restrict__ W3t, const int* __restrict__ off,
    const int* __restrict__ mtb, unsigned short* __restrict__ H) {
  __shared__ __align__(16) char lds[49152];  // A@0, B1@16384, B3@32768
  int bx = blockIdx.x;          // n-block fastest: L3-friendly expert sweep
  int by = blockIdx.y;
  if (by >= mtb[EE]) return;
  int e = 0;
  while (e < EE - 1 && mtb[e + 1] <= by) ++e;
  int m0 = off[e] + (by - mtb[e]) * 128;
  int n0 = bx * 128;
  const unsigned short* A = Xg + (size_t)m0 * DD;
  const unsigned short* B1 = W1t + ((size_t)e * FF + n0) * DD;
  const unsigned short* B3 = W3t + ((size_t)e * FF + n0) * DD;
  int tid = threadIdx.x, lane = tid & 63, wid = tid >> 6;
  int wm = wid >> 1, wn = wid & 1;
  int fr = lane & 15, fk4 = lane >> 4;
  int swz = fr & 7;
  int ce8 = (((tid & 7) ^ ((tid >> 3) & 7)) << 3);
  const unsigned short* AgT = A + (size_t)(tid >> 3) * DD + ce8;
  const unsigned short* B1T = B1 + (size_t)(tid >> 3) * DD + ce8;
  const unsigned short* B3T = B3 + (size_t)(tid >> 3) * DD + ce8;
  char* ldsW = lds + tid * 16;

  f32x4 acc1[4][4] = {}, acc3[4][4] = {};

  for (int k0 = 0; k0 < DD; k0 += 64) {
#pragma unroll
    for (int j = 0; j < 4; ++j) {
      gload16(AgT + (size_t)j * 32 * DD + k0, ldsW + j * 4096);
      gload16(B1T + (size_t)j * 32 * DD + k0, ldsW + 16384 + j * 4096);
      gload16(B3T + (size_t)j * 32 * DD + k0, ldsW + 32768 + j * 4096);
    }
    __syncthreads();
#pragma unroll
    for (int kk = 0; kk < 2; ++kk) {
      int pc = ((kk * 4 + fk4) ^ swz) << 4;  // phys chunk byte offset
      bf16x8 a[4], b1[4], b3[4];
#pragma unroll
      for (int mi = 0; mi < 4; ++mi)
        a[mi] = *(const bf16x8*)(lds + (wm * 64 + mi * 16 + fr) * 128 + pc);
#pragma unroll
      for (int ni = 0; ni < 4; ++ni) {
        b1[ni] = *(const bf16x8*)(lds + 16384 + (wn * 64 + ni * 16 + fr) * 128 + pc);
        b3[ni] = *(const bf16x8*)(lds + 32768 + (wn * 64 + ni * 16 + fr) * 128 + pc);
      }
#pragma unroll
      for (int mi = 0; mi < 4; ++mi)
#pragma unroll
        for (int ni = 0; ni < 4; ++ni) {
          acc1[mi][ni] = __builtin_amdgcn_mfma_f32_16x16x32_bf16(a[mi], b1[ni], acc1[mi][ni], 0, 0, 0);
          acc3[mi][ni] = __builtin_amdgcn_mfma_f32_16x16x32_bf16(a[mi], b3[ni], acc3[mi][ni], 0, 0, 0);
        }
    }
    __syncthreads();
  }
#pragma unroll
  for (int mi = 0; mi < 4; ++mi)
#pragma unroll
    for (int ni = 0; ni < 4; ++ni)
#pragma unroll
      for (int i = 0; i < 4; ++i) {
        int row = m0 + wm * 64 + mi * 16 + (lane >> 4) * 4 + i;
        int col = n0 + wn * 64 + ni * 16 + (lane & 15);
        float c1 = acc1[mi][ni][i], c3 = acc3[mi][ni][i];
        float h = c1 / (1.f + __expf(-c1)) * c3;
        H[(size_t)row * FF + col] = f2bf(h);
      }
}

// ---------------- GEMM2: Y = H @ W2t, 128x128, BK=64 (R8 kernel) --------------
// (256,3): acc = 64 AGPR + ~95 VGPR ~= 160 <= 170 budget -> 3 blocks/CU
// (LDS 32KB allows 5). Third co-resident block covers the barrier drain
// (m114 wave-overlap) without any intra-block pipelining.
__global__ __launch_bounds__(256, 3) void gemm2_kernel(
    const unsigned short* __restrict__ H, const unsigned short* __restrict__ W2t,
    const int* __restrict__ off, const int* __restrict__ mtb, float* __restrict__ Y) {
  __shared__ __align__(16) char lds[32768];  // A@0, B@16384
  int bx = blockIdx.x;
  int by = blockIdx.y;
  if (by >= mtb[EE]) return;
  int e = 0;
  while (e < EE - 1 && mtb[e + 1] <= by) ++e;
  int m0 = off[e] + (by - mtb[e]) * 128;
  int n0 = bx * 128;
  const unsigned short* A = H + (size_t)m0 * FF;
  const unsigned short* B = W2t + ((size_t)e * DD + n0) * FF;
  int tid = threadIdx.x, lane = tid & 63, wid = tid >> 6;
  int wm = wid >> 1, wn = wid & 1;
  int fr = lane & 15, fk4 = lane >> 4;
  int swz = fr & 7;
  int ce8 = (((tid & 7) ^ ((tid >> 3) & 7)) << 3);
  const unsigned short* AgT = A + (size_t)(tid >> 3) * FF + ce8;
  const unsigned short* BgT = B + (size_t)(tid >> 3) * FF + ce8;
  char* ldsW = lds + tid * 16;

  f32x4 acc[4][4] = {};

  for (int k0 = 0; k0 < FF; k0 += 64) {
#pragma unroll
    for (int j = 0; j < 4; ++j) {
      gload16(AgT + (size_t)j * 32 * FF + k0, ldsW + j * 4096);
      gload16(BgT + (size_t)j * 32 * FF + k0, ldsW + 16384 + j * 4096);
    }
    __syncthreads();
#pragma unroll
    for (int kk = 0; kk < 2; ++kk) {
      int pc = ((kk * 4 + fk4) ^ swz) << 4;
      bf16x8 a[4], b[4];
#pragma unroll
      for (int mi = 0; mi < 4; ++mi)
        a[mi] = *(const bf16x8*)(lds + (wm * 64 + mi * 16 + fr) * 128 + pc);
#pragma unroll
      for (int ni = 0; ni < 4; ++ni)
        b[ni] = *(const bf16x8*)(lds + 16384 + (wn * 64 + ni * 16 + fr) * 128 + pc);
#pragma unroll
      for (int mi = 0; mi < 4; ++mi)
#pragma unroll
        for (int ni = 0; ni < 4; ++ni)
          acc[mi][ni] = __builtin_amdgcn_mfma_f32_16x16x32_bf16(a[mi], b[ni], acc[mi][ni], 0, 0, 0);
    }
    __syncthreads();
  }
#pragma unroll
  for (int mi = 0; mi < 4; ++mi)
#pragma unroll
    for (int ni = 0; ni < 4; ++ni)
#pragma unroll
      for (int i = 0; i < 4; ++i) {
        int row = m0 + wm * 64 + mi * 16 + (lane >> 4) * 4 + i;
        int col = n0 + wn * 64 + ni * 16 + (lane & 15);
        Y[(size_t)row * DD + col] = acc[mi][ni][i];
      }
}

// ---------------- LayerNorm + weighted combine ---------------------------------
__global__ void ln_combine_kernel(const float* __restrict__ Y, const int* __restrict__ tok_e,
                                  const int* __restrict__ tok_s, const float* __restrict__ tok_w,
                                  const int* __restrict__ off, const float* __restrict__ gamma,
                                  const float* __restrict__ beta, float* __restrict__ out) {
  int t = blockIdx.x, tid = threadIdx.x;
  __shared__ float red[8];
  f32x4 o = {0.f, 0.f, 0.f, 0.f};
  for (int k = 0; k < 2; ++k) {
    int e = tok_e[2 * t + k], s = tok_s[2 * t + k];
    float w = tok_w[2 * t + k];
    int slot = off[e] + s;
    f32x4 v = ((const f32x4*)(Y + (size_t)slot * DD))[tid];
    float sum = v[0] + v[1] + v[2] + v[3];
    float sq = v[0] * v[0] + v[1] * v[1] + v[2] * v[2] + v[3] * v[3];
    for (int d = 32; d > 0; d >>= 1) {
      sum += __shfl_down(sum, d);
      sq += __shfl_down(sq, d);
    }
    int wv = tid >> 6, lane = tid & 63;
    if (lane == 0) { red[wv * 2] = sum; red[wv * 2 + 1] = sq; }
    __syncthreads();
    float S1 = red[0] + red[2] + red[4] + red[6];
    float S2 = red[1] + red[3] + red[5] + red[7];
    __syncthreads();
    float mu = S1 * (1.f / (float)DD);
    float var = S2 * (1.f / (float)DD) - mu * mu;
    float rs = rsqrtf(var + 1e-5f);
    f32x4 g = ((const f32x4*)(gamma + (size_t)e * DD))[tid];
    f32x4 b = ((const f32x4*)(beta + (size_t)e * DD))[tid];
#pragma unroll
    for (int j = 0; j < 4; ++j) o[j] += w * ((v[j] - mu) * rs * g[j] + b[j]);
  }
  ((f32x4*)out)[(size_t)t * (DD / 4) + tid] = o;
}

// ---------------- launch -------------------------------------------------------
extern "C" void kernel_launch(void* const* d_in, const int* in_sizes, int n_in,
                              void* d_out, int out_size, void* d_ws, size_t ws_size,
                              hipStream_t stream) {
  const float* x = (const float*)d_in[0];
  const float* Wr = (const float*)d_in[1];
  const float* br = (const float*)d_in[2];
  const float* W1 = (const float*)d_in[3];
  const float* W3 = (const float*)d_in[4];
  const float* W2 = (const float*)d_in[5];
  const float* gamma = (const float*)d_in[6];
  const float* beta = (const float*)d_in[7];
  float* out = (float*)d_out;

  char* w = (char*)d_ws;
  size_t o = 0;
  auto alloc = [&](size_t bytes) {
    void* p = w + o;
    o += (bytes + 255) & ~(size_t)255;
    return p;
  };
  int* counts = (int*)alloc(EE * 4);
  int* off = (int*)alloc((EE + 1) * 4);
  int* mtb = (int*)alloc((EE + 1) * 4);
  int* tok_e = (int*)alloc(2 * T_TOK * 4);
  int* tok_s = (int*)alloc(2 * T_TOK * 4);
  float* tok_w = (float*)alloc(2 * T_TOK * 4);
  int* elist = (int*)alloc((size_t)EE * T_TOK * 4);
  unsigned short* Xg = (unsigned short*)alloc((size_t)MAX_SLOTS * DD * 2);
  unsigned short* W1t = (unsigned short*)alloc((size_t)EE * DD * FF * 2);
  unsigned short* W3t = (unsigned short*)alloc((size_t)EE * DD * FF * 2);
  unsigned short* W2t = (unsigned short*)alloc((size_t)EE * DD * FF * 2);
  unsigned short* Hb = (unsigned short*)alloc((size_t)MAX_SLOTS * FF * 2);
  float* Y = (float*)alloc((size_t)MAX_SLOTS * DD * 4);

  hipMemsetAsync(counts, 0, EE * sizeof(int), stream);
  router_kernel<<<T_TOK / 256, 256, 0, stream>>>(x, Wr, br, counts, tok_e, tok_s, tok_w, elist);
  scan_kernel<<<1, 64, 0, stream>>>(counts, off, mtb);
  gather_kernel<<<MAX_SLOTS, 256, 0, stream>>>(x, counts, off, elist, Xg);
  transpose_conv<<<dim3(FF / 64, DD / 128, EE), 256, 0, stream>>>(W1, W1t, DD, FF);
  transpose_conv<<<dim3(FF / 64, DD / 128, EE), 256, 0, stream>>>(W3, W3t, DD, FF);
  transpose_conv<<<dim3(DD / 64, FF / 128, EE), 256, 0, stream>>>(W2, W2t, FF, DD);
  gemm1_kernel<<<dim3(FF / 128, MT), 256, 0, stream>>>(Xg, W1t, W3t, off, mtb, Hb);
  gemm2_kernel<<<dim3(DD / 128, MT), 256, 0, stream>>>(Hb, W2t, off, mtb, Y);
  ln_combine_kernel<<<T_TOK, 256, 0, stream>>>(Y, tok_e, tok_s, tok_w, off, gamma, beta, out);
}

// Round 14
// 954.418 us; speedup vs baseline: 1.0345x; 1.0106x over previous
//
#include <hip/hip_runtime.h>
#include <stdint.h>

#define T_TOK 8192
#define DD 1024
#define FF 4096
#define EE 16
#define MAX_SLOTS 18432 // 16384 + 16*127 padded to 128
#define MT 144          // max 128-row m-tiles

typedef __attribute__((ext_vector_type(4))) float f32x4;
typedef __attribute__((ext_vector_type(8))) short bf16x8;

__device__ __forceinline__ unsigned short f2bf(float f) {
  union { float f; unsigned u; } v; v.f = f;
  unsigned r = v.u + 0x7FFFu + ((v.u >> 16) & 1u);
  return (unsigned short)(r >> 16);
}

__device__ __forceinline__ float bf2f(unsigned short b) {
  union { unsigned u; float f; } v; v.u = ((unsigned)b) << 16;
  return v.f;
}

__device__ __forceinline__ void gload16(const void* g, void* l) {
  __builtin_amdgcn_global_load_lds(
      (const __attribute__((address_space(1))) unsigned int*)g,
      (__attribute__((address_space(3))) unsigned int*)l, 16, 0, 0);
}

// ---------------- router ------------------------------------------------------
__global__ void router_kernel(const float* __restrict__ x, const float* __restrict__ Wr,
                              const float* __restrict__ br,
                              int* __restrict__ counts, int* __restrict__ tok_e,
                              int* __restrict__ tok_s, float* __restrict__ tok_w,
                              int* __restrict__ elist) {
  int t = blockIdx.x * blockDim.x + threadIdx.x;
  if (t >= T_TOK) return;
  float acc[EE];
#pragma unroll
  for (int e = 0; e < EE; ++e) acc[e] = br[e];
  const f32x4* x4 = (const f32x4*)(x + (size_t)t * DD);
  for (int d4 = 0; d4 < DD / 4; ++d4) {
    f32x4 xv = x4[d4];
    const float* wr = Wr + (size_t)d4 * 4 * EE;
#pragma unroll
    for (int dd = 0; dd < 4; ++dd)
#pragma unroll
      for (int e = 0; e < EE; ++e) acc[e] += xv[dd] * wr[dd * EE + e];
  }
  int i0 = 0; float v0 = acc[0];
#pragma unroll
  for (int e = 1; e < EE; ++e) if (acc[e] > v0) { v0 = acc[e]; i0 = e; }
  int i1 = -1; float v1 = -3.4e38f;
#pragma unroll
  for (int e = 0; e < EE; ++e) if (e != i0 && acc[e] > v1) { v1 = acc[e]; i1 = e; }
  float p1 = __expf(v1 - v0);
  float w0 = 1.f / (1.f + p1);
  float w1 = p1 * w0;
  int s0 = atomicAdd(&counts[i0], 1);
  int s1 = atomicAdd(&counts[i1], 1);
  tok_e[2 * t] = i0; tok_s[2 * t] = s0; tok_w[2 * t] = w0;
  tok_e[2 * t + 1] = i1; tok_s[2 * t + 1] = s1; tok_w[2 * t + 1] = w1;
  elist[(size_t)i0 * T_TOK + s0] = t;
  elist[(size_t)i1 * T_TOK + s1] = t;
}

// ---------------- scan (pad to 128) -------------------------------------------
__global__ void scan_kernel(const int* __restrict__ counts, int* __restrict__ off,
                            int* __restrict__ mtb) {
  if (threadIdx.x == 0 && blockIdx.x == 0) {
    int o = 0, m = 0;
    for (int e = 0; e < EE; ++e) {
      off[e] = o; mtb[e] = m;
      int c = counts[e];
      int mt = (c + 127) / 128;
      o += mt * 128; m += mt;
    }
    off[EE] = o; mtb[EE] = m;
  }
}

// ---------------- gather ------------------------------------------------------
__global__ void gather_kernel(const float* __restrict__ x, const int* __restrict__ counts,
                              const int* __restrict__ off, const int* __restrict__ elist,
                              unsigned short* __restrict__ Xg) {
  int slot = blockIdx.x;
  if (slot >= off[EE]) return;
  int e = 0;
  while (e < EE - 1 && off[e + 1] <= slot) ++e;
  int s = slot - off[e];
  int tid = threadIdx.x;
  ushort4* dst = (ushort4*)(Xg + (size_t)slot * DD);
  if (s < counts[e]) {
    int t = elist[(size_t)e * T_TOK + s];
    f32x4 v = ((const f32x4*)(x + (size_t)t * DD))[tid];
    ushort4 o;
    o.x = f2bf(v[0]); o.y = f2bf(v[1]); o.z = f2bf(v[2]); o.w = f2bf(v[3]);
    dst[tid] = o;
  } else {
    ushort4 z; z.x = z.y = z.z = z.w = 0;
    dst[tid] = z;
  }
}

// ---------------- fused transpose+convert: W1, W3, W2 in one launch -----------
// z in [0,16): W1 e=z (R=DD,C=FF); [16,32): W3; [32,48): W2 (R=FF,C=DD with
// grid remap since its tile grid is 16x32 vs W13's 64x8).
__global__ void transpose_all(const float* __restrict__ W1, const float* __restrict__ W3,
                              const float* __restrict__ W2,
                              unsigned short* __restrict__ W1t, unsigned short* __restrict__ W3t,
                              unsigned short* __restrict__ W2t) {
  __shared__ float tile[128][65];
  int z = blockIdx.z;
  const float* src; unsigned short* dst; int R, C, bx, by;
  if (z < 32) {
    int e = z & 15;
    R = DD; C = FF; bx = blockIdx.x; by = blockIdx.y;
    src = (z < 16 ? W1 : W3) + (size_t)e * R * C;
    dst = (z < 16 ? W1t : W3t) + (size_t)e * R * C;
  } else {
    int e = z - 32;
    R = FF; C = DD;
    int flat = blockIdx.y * 64 + blockIdx.x;  // [0,512)
    bx = flat & 15; by = flat >> 4;           // 16 x 32
    src = W2 + (size_t)e * R * C;
    dst = W2t + (size_t)e * R * C;
  }
  int r0 = by * 128, c0 = bx * 64;
  int tid = threadIdx.x;
  int lc = (tid & 15) * 4, lr = tid >> 4;
#pragma unroll
  for (int p = 0; p < 8; ++p) {
    int r = p * 16 + lr;
    f32x4 v = *(const f32x4*)(src + (size_t)(r0 + r) * C + c0 + lc);
    tile[r][lc + 0] = v[0]; tile[r][lc + 1] = v[1];
    tile[r][lc + 2] = v[2]; tile[r][lc + 3] = v[3];
  }
  __syncthreads();
  int sc = tid >> 4, sr = (tid & 15) * 8;
#pragma unroll
  for (int p = 0; p < 4; ++p) {
    int c = p * 16 + sc;
    unsigned short tmp[8];
#pragma unroll
    for (int j = 0; j < 8; ++j) tmp[j] = f2bf(tile[sr + j][c]);
    *(bf16x8*)(dst + (size_t)(c0 + c) * R + r0 + sr) = *(const bf16x8*)tmp;
  }
}

// ---------------- GEMM1: 128x128, BK=64, swizzled LDS (R8-proven) -------------
// LDS panels [128 rows][128B]: LDS[row][chunk ch] = G[row][k0 + (ch^(row&7))*8]
// (both-sides swizzle). Fragment read chunk lc = kk*4 + (lane>>4); phys = lc^(fr&7).
// (256,2): acc1+acc3 = 128 AGPR + ~100 VGPR = 228 -> 2 waves/SIMD, NO spill.
__global__ __launch_bounds__(256, 2) void gemm1_kernel(
    const unsigned short* __restrict__ Xg, const unsigned short* __restrict__ W1t,
    const unsigned short* __restrict__ W3t, const int* __restrict__ off,
    const int* __restrict__ mtb, unsigned short* __restrict__ H) {
  __shared__ __align__(16) char lds[49152];  // A@0, B1@16384, B3@32768
  int bx = blockIdx.x;          // n-block fastest: L3-friendly expert sweep
  int by = blockIdx.y;
  if (by >= mtb[EE]) return;
  int e = 0;
  while (e < EE - 1 && mtb[e + 1] <= by) ++e;
  int m0 = off[e] + (by - mtb[e]) * 128;
  int n0 = bx * 128;
  const unsigned short* A = Xg + (size_t)m0 * DD;
  const unsigned short* B1 = W1t + ((size_t)e * FF + n0) * DD;
  const unsigned short* B3 = W3t + ((size_t)e * FF + n0) * DD;
  int tid = threadIdx.x, lane = tid & 63, wid = tid >> 6;
  int wm = wid >> 1, wn = wid & 1;
  int fr = lane & 15, fk4 = lane >> 4;
  int swz = fr & 7;
  int ce8 = (((tid & 7) ^ ((tid >> 3) & 7)) << 3);
  const unsigned short* AgT = A + (size_t)(tid >> 3) * DD + ce8;
  const unsigned short* B1T = B1 + (size_t)(tid >> 3) * DD + ce8;
  const unsigned short* B3T = B3 + (size_t)(tid >> 3) * DD + ce8;
  char* ldsW = lds + tid * 16;

  f32x4 acc1[4][4] = {}, acc3[4][4] = {};

  for (int k0 = 0; k0 < DD; k0 += 64) {
#pragma unroll
    for (int j = 0; j < 4; ++j) {
      gload16(AgT + (size_t)j * 32 * DD + k0, ldsW + j * 4096);
      gload16(B1T + (size_t)j * 32 * DD + k0, ldsW + 16384 + j * 4096);
      gload16(B3T + (size_t)j * 32 * DD + k0, ldsW + 32768 + j * 4096);
    }
    __syncthreads();
#pragma unroll
    for (int kk = 0; kk < 2; ++kk) {
      int pc = ((kk * 4 + fk4) ^ swz) << 4;  // phys chunk byte offset
      bf16x8 a[4], b1[4], b3[4];
#pragma unroll
      for (int mi = 0; mi < 4; ++mi)
        a[mi] = *(const bf16x8*)(lds + (wm * 64 + mi * 16 + fr) * 128 + pc);
#pragma unroll
      for (int ni = 0; ni < 4; ++ni) {
        b1[ni] = *(const bf16x8*)(lds + 16384 + (wn * 64 + ni * 16 + fr) * 128 + pc);
        b3[ni] = *(const bf16x8*)(lds + 32768 + (wn * 64 + ni * 16 + fr) * 128 + pc);
      }
#pragma unroll
      for (int mi = 0; mi < 4; ++mi)
#pragma unroll
        for (int ni = 0; ni < 4; ++ni) {
          acc1[mi][ni] = __builtin_amdgcn_mfma_f32_16x16x32_bf16(a[mi], b1[ni], acc1[mi][ni], 0, 0, 0);
          acc3[mi][ni] = __builtin_amdgcn_mfma_f32_16x16x32_bf16(a[mi], b3[ni], acc3[mi][ni], 0, 0, 0);
        }
    }
    __syncthreads();
  }
#pragma unroll
  for (int mi = 0; mi < 4; ++mi)
#pragma unroll
    for (int ni = 0; ni < 4; ++ni)
#pragma unroll
      for (int i = 0; i < 4; ++i) {
        int row = m0 + wm * 64 + mi * 16 + (lane >> 4) * 4 + i;
        int col = n0 + wn * 64 + ni * 16 + (lane & 15);
        float c1 = acc1[mi][ni][i], c3 = acc3[mi][ni][i];
        float h = c1 / (1.f + __expf(-c1)) * c3;
        H[(size_t)row * FF + col] = f2bf(h);
      }
}

// ---------------- GEMM2: Y(bf16) = H @ W2t, 128x128, BK=64 --------------------
// (256,3): acc = 64 AGPR + ~95 VGPR ~= 160 -> 3 blocks/CU (R13-proven win).
__global__ __launch_bounds__(256, 3) void gemm2_kernel(
    const unsigned short* __restrict__ H, const unsigned short* __restrict__ W2t,
    const int* __restrict__ off, const int* __restrict__ mtb,
    unsigned short* __restrict__ Y) {
  __shared__ __align__(16) char lds[32768];  // A@0, B@16384
  int bx = blockIdx.x;
  int by = blockIdx.y;
  if (by >= mtb[EE]) return;
  int e = 0;
  while (e < EE - 1 && mtb[e + 1] <= by) ++e;
  int m0 = off[e] + (by - mtb[e]) * 128;
  int n0 = bx * 128;
  const unsigned short* A = H + (size_t)m0 * FF;
  const unsigned short* B = W2t + ((size_t)e * DD + n0) * FF;
  int tid = threadIdx.x, lane = tid & 63, wid = tid >> 6;
  int wm = wid >> 1, wn = wid & 1;
  int fr = lane & 15, fk4 = lane >> 4;
  int swz = fr & 7;
  int ce8 = (((tid & 7) ^ ((tid >> 3) & 7)) << 3);
  const unsigned short* AgT = A + (size_t)(tid >> 3) * FF + ce8;
  const unsigned short* BgT = B + (size_t)(tid >> 3) * FF + ce8;
  char* ldsW = lds + tid * 16;

  f32x4 acc[4][4] = {};

  for (int k0 = 0; k0 < FF; k0 += 64) {
#pragma unroll
    for (int j = 0; j < 4; ++j) {
      gload16(AgT + (size_t)j * 32 * FF + k0, ldsW + j * 4096);
      gload16(BgT + (size_t)j * 32 * FF + k0, ldsW + 16384 + j * 4096);
    }
    __syncthreads();
#pragma unroll
    for (int kk = 0; kk < 2; ++kk) {
      int pc = ((kk * 4 + fk4) ^ swz) << 4;
      bf16x8 a[4], b[4];
#pragma unroll
      for (int mi = 0; mi < 4; ++mi)
        a[mi] = *(const bf16x8*)(lds + (wm * 64 + mi * 16 + fr) * 128 + pc);
#pragma unroll
      for (int ni = 0; ni < 4; ++ni)
        b[ni] = *(const bf16x8*)(lds + 16384 + (wn * 64 + ni * 16 + fr) * 128 + pc);
#pragma unroll
      for (int mi = 0; mi < 4; ++mi)
#pragma unroll
        for (int ni = 0; ni < 4; ++ni)
          acc[mi][ni] = __builtin_amdgcn_mfma_f32_16x16x32_bf16(a[mi], b[ni], acc[mi][ni], 0, 0, 0);
    }
    __syncthreads();
  }
#pragma unroll
  for (int mi = 0; mi < 4; ++mi)
#pragma unroll
    for (int ni = 0; ni < 4; ++ni)
#pragma unroll
      for (int i = 0; i < 4; ++i) {
        int row = m0 + wm * 64 + mi * 16 + (lane >> 4) * 4 + i;
        int col = n0 + wn * 64 + ni * 16 + (lane & 15);
        Y[(size_t)row * DD + col] = f2bf(acc[mi][ni][i]);
      }
}

// ---------------- LayerNorm + weighted combine (bf16 Y) ------------------------
__global__ void ln_combine_kernel(const unsigned short* __restrict__ Y,
                                  const int* __restrict__ tok_e,
                                  const int* __restrict__ tok_s, const float* __restrict__ tok_w,
                                  const int* __restrict__ off, const float* __restrict__ gamma,
                                  const float* __restrict__ beta, float* __restrict__ out) {
  int t = blockIdx.x, tid = threadIdx.x;
  __shared__ float red[8];
  f32x4 o = {0.f, 0.f, 0.f, 0.f};
  for (int k = 0; k < 2; ++k) {
    int e = tok_e[2 * t + k], s = tok_s[2 * t + k];
    float w = tok_w[2 * t + k];
    int slot = off[e] + s;
    ushort4 vb = ((const ushort4*)(Y + (size_t)slot * DD))[tid];
    f32x4 v;
    v[0] = bf2f(vb.x); v[1] = bf2f(vb.y); v[2] = bf2f(vb.z); v[3] = bf2f(vb.w);
    float sum = v[0] + v[1] + v[2] + v[3];
    float sq = v[0] * v[0] + v[1] * v[1] + v[2] * v[2] + v[3] * v[3];
    for (int d = 32; d > 0; d >>= 1) {
      sum += __shfl_down(sum, d);
      sq += __shfl_down(sq, d);
    }
    int wv = tid >> 6, lane = tid & 63;
    if (lane == 0) { red[wv * 2] = sum; red[wv * 2 + 1] = sq; }
    __syncthreads();
    float S1 = red[0] + red[2] + red[4] + red[6];
    float S2 = red[1] + red[3] + red[5] + red[7];
    __syncthreads();
    float mu = S1 * (1.f / (float)DD);
    float var = S2 * (1.f / (float)DD) - mu * mu;
    float rs = rsqrtf(var + 1e-5f);
    f32x4 g = ((const f32x4*)(gamma + (size_t)e * DD))[tid];
    f32x4 b = ((const f32x4*)(beta + (size_t)e * DD))[tid];
#pragma unroll
    for (int j = 0; j < 4; ++j) o[j] += w * ((v[j] - mu) * rs * g[j] + b[j]);
  }
  ((f32x4*)out)[(size_t)t * (DD / 4) + tid] = o;
}

// ---------------- launch -------------------------------------------------------
extern "C" void kernel_launch(void* const* d_in, const int* in_sizes, int n_in,
                              void* d_out, int out_size, void* d_ws, size_t ws_size,
                              hipStream_t stream) {
  const float* x = (const float*)d_in[0];
  const float* Wr = (const float*)d_in[1];
  const float* br = (const float*)d_in[2];
  const float* W1 = (const float*)d_in[3];
  const float* W3 = (const float*)d_in[4];
  const float* W2 = (const float*)d_in[5];
  const float* gamma = (const float*)d_in[6];
  const float* beta = (const float*)d_in[7];
  float* out = (float*)d_out;

  char* w = (char*)d_ws;
  size_t o = 0;
  auto alloc = [&](size_t bytes) {
    void* p = w + o;
    o += (bytes + 255) & ~(size_t)255;
    return p;
  };
  int* counts = (int*)alloc(EE * 4);
  int* off = (int*)alloc((EE + 1) * 4);
  int* mtb = (int*)alloc((EE + 1) * 4);
  int* tok_e = (int*)alloc(2 * T_TOK * 4);
  int* tok_s = (int*)alloc(2 * T_TOK * 4);
  float* tok_w = (float*)alloc(2 * T_TOK * 4);
  int* elist = (int*)alloc((size_t)EE * T_TOK * 4);
  unsigned short* Xg = (unsigned short*)alloc((size_t)MAX_SLOTS * DD * 2);
  unsigned short* W1t = (unsigned short*)alloc((size_t)EE * DD * FF * 2);
  unsigned short* W3t = (unsigned short*)alloc((size_t)EE * DD * FF * 2);
  unsigned short* W2t = (unsigned short*)alloc((size_t)EE * DD * FF * 2);
  unsigned short* Hb = (unsigned short*)alloc((size_t)MAX_SLOTS * FF * 2);
  unsigned short* Y = (unsigned short*)alloc((size_t)MAX_SLOTS * DD * 2);

  hipMemsetAsync(counts, 0, EE * sizeof(int), stream);
  router_kernel<<<T_TOK / 256, 256, 0, stream>>>(x, Wr, br, counts, tok_e, tok_s, tok_w, elist);
  scan_kernel<<<1, 64, 0, stream>>>(counts, off, mtb);
  gather_kernel<<<MAX_SLOTS, 256, 0, stream>>>(x, counts, off, elist, Xg);
  transpose_all<<<dim3(FF / 64, DD / 128, 48), 256, 0, stream>>>(W1, W3, W2, W1t, W3t, W2t);
  gemm1_kernel<<<dim3(FF / 128, MT), 256, 0, stream>>>(Xg, W1t, W3t, off, mtb, Hb);
  gemm2_kernel<<<dim3(DD / 128, MT), 256, 0, stream>>>(Hb, W2t, off, mtb, Y);
  ln_combine_kernel<<<T_TOK, 256, 0, stream>>>(Y, tok_e, tok_s, tok_w, off, gamma, beta, out);
}